// Round 8
// baseline (361.605 us; speedup 1.0000x reference)
//
#include <hip/hip_runtime.h>

#define B_SZ 16
#define S_SZ 8192
#define H_SZ 256

typedef _Float16 half8 __attribute__((ext_vector_type(8)));
typedef float f32x4 __attribute__((ext_vector_type(4)));

__device__ __forceinline__ float tanh_fast(float x) {
  // tanh(x) = 1 - 2/(e^{2x}+1); saturates correctly at +-inf.
  float e = __expf(2.0f * x);
  return 1.0f - 2.0f / (e + 1.0f);
}

// ---------------------------------------------------------------------------
// Phase A: qb[b,o] = dot(query[b,:], Wq[o,:]) + b_attn[o]  (qb -> ctx slot,
// consumed by fused kernel, overwritten by combine with final context).
// ---------------------------------------------------------------------------
__global__ __launch_bounds__(256) void prep_kernel(
    const float* __restrict__ query, const float* __restrict__ W_attn,
    const float* __restrict__ b_attn, float* __restrict__ qb) {
  const int b = blockIdx.x;
  const int jo = blockIdx.y;
  const int wid = threadIdx.x >> 6;
  const int lane = threadIdx.x & 63;
  const float4 q4 = *(const float4*)(query + b * H_SZ + lane * 4);
#pragma unroll 4
  for (int i = 0; i < 16; i++) {
    const int o = jo * 64 + wid * 16 + i;
    const float4 w = *(const float4*)(W_attn + (size_t)o * 512 + lane * 4);
    float p = q4.x * w.x + q4.y * w.y + q4.z * w.z + q4.w * w.w;
#pragma unroll
    for (int off = 32; off >= 1; off >>= 1) p += __shfl_xor(p, off, 64);
    if (lane == 0) qb[b * H_SZ + o] = p + b_attn[o];
  }
}

// ---------------------------------------------------------------------------
// Fused scores+softmax+context, v6. 512 blocks x 512 threads (8 waves).
// Reuse-oriented reshape of v3b: each wave owns TWO 16-o MFMA tiles, so
// every ds_read_b128 bfrag feeds 2 MFMAs (DS-read traffic halved vs the
// 16-wave/1-tile structure; cross-wave shuffle+atomic traffic also halved;
// 8-wave barrier domains instead of 16). Register diet vs the failed v2:
//  - (qb, v) pairs live in a 2 KiB LDS table, not 16 VGPRs;
//  - key staging is two sequential 8-reg passes using v1's proven
//    0-conflict XOR geometry per pass;
//  - value rows fold as two pairs (8 regs in flight each).
// Per-chunk psum[8][32] + redundant per-wave online softmax as in v3b.
// ---------------------------------------------------------------------------
__global__ __launch_bounds__(512, 4) void fused_kernel(
    const float* __restrict__ key, const float* __restrict__ value,
    const float* __restrict__ W_attn, const float* __restrict__ qb,
    const float* __restrict__ vvec, float* __restrict__ scores,
    float* __restrict__ ctxp, float* __restrict__ mblk,
    float* __restrict__ zblk) {
  __shared__ __align__(16) _Float16 kbuf[2][32 * 256];  // 2 x 16 KiB staging
  __shared__ float psum[8][32];                         // per-chunk scores
  __shared__ float2 qv[256];                            // (qb, v) per o
  __shared__ float4 comb[8][64];                        // epilogue (8 KiB)

  const int tid = threadIdx.x;
  const int w = tid >> 6;      // wave 0..7, owns o-tiles 2w, 2w+1
  const int lane = tid & 63;
  const int n = lane & 15;     // A row (o within tile) / D column (key row)
  const int quad = lane >> 4;
  const int rowBase = blockIdx.x * 256;
  const int b = blockIdx.x >> 5;  // 32 blocks per batch

  // A fragments: Wk[o][k], o = (2w+ot)*16 + n, k = ks*32 + quad*8 + j.
  half8 afrag[2][8];
#pragma unroll
  for (int ot = 0; ot < 2; ot++) {
    const float* wrow =
        W_attn + (size_t)(w * 32 + ot * 16 + n) * 512 + 256 + quad * 8;
#pragma unroll
    for (int ks = 0; ks < 8; ks++) {
      float4 f0 = *(const float4*)(wrow + ks * 32);
      float4 f1 = *(const float4*)(wrow + ks * 32 + 4);
      half8 a;
      a[0] = (_Float16)f0.x; a[1] = (_Float16)f0.y;
      a[2] = (_Float16)f0.z; a[3] = (_Float16)f0.w;
      a[4] = (_Float16)f1.x; a[5] = (_Float16)f1.y;
      a[6] = (_Float16)f1.z; a[7] = (_Float16)f1.w;
      afrag[ot][ks] = a;
    }
  }
  // (qb, v) table + psum zero-init.
  if (tid < 256) {
    qv[tid] = make_float2(qb[b * H_SZ + tid], vvec[tid]);
    ((float*)psum)[tid] = 0.f;
  }

  // Key staging: two passes of (16 rows x 32 segs x 8 f32), XOR-swizzled —
  // v1's exact conflict-free geometry per pass.
  const int sseg = tid & 31;
  const int srow0 = tid >> 5;        // pass 0: rows 0..15
  const int srow1 = srow0 + 16;      // pass 1: rows 16..31
  const size_t sb0 = (size_t)(rowBase + srow0) * H_SZ + sseg * 8;
  const size_t sb1 = (size_t)(rowBase + srow1) * H_SZ + sseg * 8;
  const int sd0 = srow0 * 256 + ((sseg ^ srow0) << 3);
  const int sd1 = srow1 * 256 + ((sseg ^ srow1) << 3);

  // Value: wave w owns rows 4w..4w+3 of each chunk; lane = float4 column.
  const float* vbase = value + (size_t)(rowBase + 4 * w) * H_SZ + lane * 4;

#define STAGE_PASS(buf, sb, sd, coff)                                   \
  do {                                                                  \
    float4 f0 = *(const float4*)(key + (sb) + (coff));                  \
    float4 f1 = *(const float4*)(key + (sb) + (coff) + 4);              \
    half8 h;                                                            \
    h[0] = (_Float16)f0.x; h[1] = (_Float16)f0.y;                       \
    h[2] = (_Float16)f0.z; h[3] = (_Float16)f0.w;                       \
    h[4] = (_Float16)f1.x; h[5] = (_Float16)f1.y;                       \
    h[6] = (_Float16)f1.z; h[7] = (_Float16)f1.w;                       \
    *(half8*)&kbuf[buf][sd] = h;                                        \
  } while (0)

  // Prologue: stage key chunk 0.
  STAGE_PASS(0, sb0, sd0, 0);
  STAGE_PASS(0, sb1, sd1, 0);
  __syncthreads();

  float4 acc4 = {0.f, 0.f, 0.f, 0.f};  // this wave's value accumulator
  float m_run = -1e30f;                // redundant per-wave running max
  float z_run = 0.f;                   // meaningful only in wave 0

  for (int c = 0; c < 8; c++) {
    const size_t coff = (size_t)c * 32 * H_SZ;
    // Value pair A for chunk c (rows 4w, 4w+1).
    const float4 va0 = *(const float4*)(vbase + coff);
    const float4 va1 = *(const float4*)(vbase + coff + H_SZ);

    const _Float16* kb = kbuf[c & 1];
#pragma unroll
    for (int rt = 0; rt < 2; rt++) {
      const int lrow = rt * 16 + n;  // key row within chunk (D column)
      f32x4 acc0 = {0.f, 0.f, 0.f, 0.f};
      f32x4 acc1 = {0.f, 0.f, 0.f, 0.f};
#pragma unroll
      for (int ks = 0; ks < 8; ks++) {
        half8 bfrag =
            *(const half8*)&kb[lrow * 256 + (((ks * 4 + quad) ^ lrow) << 3)];
        acc0 = __builtin_amdgcn_mfma_f32_16x16x32_f16(afrag[0][ks], bfrag,
                                                      acc0, 0, 0, 0);
        acc1 = __builtin_amdgcn_mfma_f32_16x16x32_f16(afrag[1][ks], bfrag,
                                                      acc1, 0, 0, 0);
      }
      float p = 0.f;
#pragma unroll
      for (int rg = 0; rg < 4; rg++) {
        const int o0 = w * 32 + quad * 4 + rg;
        const float2 q0 = qv[o0];
        const float2 q1 = qv[o0 + 16];
        p = fmaf(q0.y, tanh_fast(q0.x + acc0[rg]), p);
        p = fmaf(q1.y, tanh_fast(q1.x + acc1[rg]), p);
      }
      // Sum over the 4 quads (same key row, different o-subsets).
      p += __shfl_xor(p, 16, 64);
      p += __shfl_xor(p, 32, 64);
      if (quad == 0) atomicAdd(&psum[c][lrow], p);
    }
    // Value pair B (rows 4w+2, 4w+3): in flight during publish + barrier.
    const float4 vb0 = *(const float4*)(vbase + coff + 2 * H_SZ);
    const float4 vb1 = *(const float4*)(vbase + coff + 3 * H_SZ);
    if (c < 7) {  // stage key chunk c+1 (two passes)
      const size_t noff = coff + 32 * H_SZ;
      STAGE_PASS((c + 1) & 1, sb0, sd0, noff);
      STAGE_PASS((c + 1) & 1, sb1, sd1, noff);
    }
    __syncthreads();  // psum[c] complete; key chunk c+1 published.

    // Redundant per-wave online softmax (identical in every wave).
    const float sv = psum[c][lane & 31];
    float cm = sv;
#pragma unroll
    for (int off = 16; off >= 1; off >>= 1)
      cm = fmaxf(cm, __shfl_xor(cm, off, 64));
    const float m_new = fmaxf(m_run, cm);
    const float scl = __expf(m_run - m_new);  // 0 on first chunk
    m_run = m_new;
    const float wl = __expf(sv - m_new);
    if (w == 0) {  // raw scores + running Z (nobody waits on this)
      if (lane < 32) scores[rowBase + c * 32 + lane] = sv;
      float zc = wl;
#pragma unroll
      for (int off = 16; off >= 1; off >>= 1) zc += __shfl_xor(zc, off, 64);
      z_run = fmaf(z_run, scl, zc);
    }
    // Weights for this wave's 4 value rows (broadcast from lanes 4w..4w+3).
    const float w0 = __shfl(wl, 4 * w + 0, 64);
    const float w1 = __shfl(wl, 4 * w + 1, 64);
    const float w2 = __shfl(wl, 4 * w + 2, 64);
    const float w3 = __shfl(wl, 4 * w + 3, 64);
    acc4.x = fmaf(w3, vb1.x,
             fmaf(w2, vb0.x, fmaf(w1, va1.x, fmaf(w0, va0.x, acc4.x * scl))));
    acc4.y = fmaf(w3, vb1.y,
             fmaf(w2, vb0.y, fmaf(w1, va1.y, fmaf(w0, va0.y, acc4.y * scl))));
    acc4.z = fmaf(w3, vb1.z,
             fmaf(w2, vb0.z, fmaf(w1, va1.z, fmaf(w0, va0.z, acc4.z * scl))));
    acc4.w = fmaf(w3, vb1.w,
             fmaf(w2, vb0.w, fmaf(w1, va1.w, fmaf(w0, va0.w, acc4.w * scl))));
  }
#undef STAGE_PASS

  // Epilogue: combine 8 wave accumulators; write per-block partials.
  comb[w][lane] = acc4;
  __syncthreads();
  if (tid < 64) {
    float4 t4 = comb[0][tid];
#pragma unroll
    for (int j = 1; j < 8; j++) {
      const float4 u = comb[j][tid];
      t4.x += u.x; t4.y += u.y; t4.z += u.z; t4.w += u.w;
    }
    *(float4*)(ctxp + (size_t)blockIdx.x * 256 + tid * 4) = t4;
  }
  if (tid == 0) {
    mblk[blockIdx.x] = m_run;
    zblk[blockIdx.x] = z_run;
  }
}

// ---------------------------------------------------------------------------
// Combine: per batch, merge the 32 block partials -> global m, Z, context.
// Publishes (m, Z) for the normalize pass. 16 blocks x 256 threads.
// ---------------------------------------------------------------------------
__global__ __launch_bounds__(256) void combine_kernel(
    const float* __restrict__ ctxp, const float* __restrict__ mblk,
    const float* __restrict__ zblk, float* __restrict__ ctx,
    float* __restrict__ mf, float* __restrict__ zf) {
  const int b = blockIdx.x;
  const int t = threadIdx.x;
  __shared__ float ms[32], zs[32];
  if (t < 32) {
    ms[t] = mblk[b * 32 + t];
    zs[t] = zblk[b * 32 + t];
  }
  __syncthreads();
  float m = -1e30f;
#pragma unroll
  for (int j = 0; j < 32; j++) m = fmaxf(m, ms[j]);
  float Z = 0.f;
  float e[32];  // fully unrolled -> registers (no scratch)
#pragma unroll
  for (int j = 0; j < 32; j++) {
    e[j] = __expf(ms[j] - m);
    Z = fmaf(zs[j], e[j], Z);
  }
  float acc = 0.f;
#pragma unroll
  for (int j = 0; j < 32; j++)
    acc = fmaf(ctxp[(size_t)(b * 32 + j) * 256 + t], e[j], acc);
  ctx[b * H_SZ + t] = acc / Z;
  if (t == 0) {
    mf[b] = m;
    zf[b] = Z;
  }
}

// ---------------------------------------------------------------------------
// Normalize: attn[b,s] = exp(raw - m_b) / Z_b, in place. 256 blocks x 512.
// ---------------------------------------------------------------------------
__global__ __launch_bounds__(512) void normalize_kernel(
    const float* __restrict__ mf, const float* __restrict__ zf,
    float* __restrict__ attn) {
  const int b = blockIdx.x;
  const int j = blockIdx.y;
  const float m = mf[b];
  const float invZ = 1.0f / zf[b];
  const int idx = j * 512 + threadIdx.x;
  float* arow = attn + (size_t)b * S_SZ;
  arow[idx] = __expf(arow[idx] - m) * invZ;
}

// ---------------------------------------------------------------------------
extern "C" void kernel_launch(void* const* d_in, const int* in_sizes, int n_in,
                              void* d_out, int out_size, void* d_ws,
                              size_t ws_size, hipStream_t stream) {
  const float* query = (const float*)d_in[0];   // (16,1,256)
  const float* key = (const float*)d_in[1];     // (16,8192,256)
  const float* value = (const float*)d_in[2];   // (16,8192,256)
  const float* W_attn = (const float*)d_in[3];  // (256,512)
  const float* b_attn = (const float*)d_in[4];  // (256,)
  const float* vvec = (const float*)d_in[5];    // (256,)

  float* out = (float*)d_out;
  float* ctx = out;          // 16*256 (qb scratch, then final context)
  float* attn = out + 4096;  // 16*8192 (raw scores -> weights in place)
  float* ctxp = (float*)d_ws;            // 512*256 per-block partial contexts
  float* mblk = ctxp + 512 * 256;        // 512 per-block maxes
  float* zblk = mblk + 512;              // 512 per-block partition sums
  float* mf = zblk + 512;                // 16 final maxes
  float* zf = mf + 16;                   // 16 final Z

  prep_kernel<<<dim3(B_SZ, 4), 256, 0, stream>>>(query, W_attn, b_attn, ctx);
  fused_kernel<<<512, 512, 0, stream>>>(key, value, W_attn, ctx, vvec, attn,
                                        ctxp, mblk, zblk);
  combine_kernel<<<B_SZ, 256, 0, stream>>>(ctxp, mblk, zblk, ctx, mf, zf);
  normalize_kernel<<<dim3(B_SZ, 16), 512, 0, stream>>>(mf, zf, attn);
}